// Round 13
// baseline (22068.365 us; speedup 1.0000x reference)
//
#include <hip/hip_runtime.h>

#define NWG   256
#define TPB_R 256     // resident kernel: 4 waves, 1/SIMD -> 256-VGPR budget (proven r10)
#define TPB_S 1024    // fallback streaming kernel
#define NSTEP 1000
#define NDATA 2048
#define WIDTH 4096

typedef __attribute__((ext_vector_type(4))) float f32x4;
typedef __attribute__((ext_vector_type(2))) float f32x2;
typedef __attribute__((ext_vector_type(2))) unsigned int u32x2;
typedef __attribute__((ext_vector_type(4))) unsigned int u32x4;
typedef unsigned int uint;

#define SCHED_FENCE() __builtin_amdgcn_sched_barrier(0)

// ---------- scalar helpers ----------

__device__ __forceinline__ float sp_f(float v) {
  // jax.nn.softplus == max(v,0) + log1p(exp(-|v|))
  return fmaxf(v, 0.0f) + log1pf(expf(-fabsf(v)));
}

__device__ __forceinline__ float wred(float v) {
#pragma unroll
  for (int m = 32; m > 0; m >>= 1) v += __shfl_xor(v, m, 64);
  return v;
}

// ---------- waits / barriers ----------

__device__ __forceinline__ void wait_vm0()   { asm volatile("s_waitcnt vmcnt(0)" ::: "memory"); SCHED_FENCE(); }
template<int N>
__device__ __forceinline__ void wait_vmN()   { asm volatile("s_waitcnt vmcnt(%0)" :: "n"(N) : "memory"); SCHED_FENCE(); }
__device__ __forceinline__ void wait_lgkm0() { asm volatile("s_waitcnt lgkmcnt(0)" ::: "memory"); SCHED_FENCE(); }
__device__ __forceinline__ void wgbar()      { __builtin_amdgcn_s_barrier(); SCHED_FENCE(); }

// ---------- L2-bypass (IC-coherent) I/O: sc0 sc1 ----------

__device__ __forceinline__ void st_sc_x1(float* p, float v) {
  asm volatile("global_store_dword %0, %1, off sc0 sc1" :: "v"(p), "v"(v) : "memory");
}
__device__ __forceinline__ void st_sc_x2(float* p, f32x2 v) {
  asm volatile("global_store_dwordx2 %0, %1, off sc0 sc1" :: "v"(p), "v"(v) : "memory");
}
__device__ __forceinline__ void st_sc_x4(float* p, f32x4 v) {
  asm volatile("global_store_dwordx4 %0, %1, off sc0 sc1" :: "v"(p), "v"(v) : "memory");
}
__device__ __forceinline__ void ld_sc_x2_issue(const float* p, f32x2& v) {
  asm volatile("global_load_dwordx2 %0, %1, off sc0 sc1" : "=v"(v) : "v"(p) : "memory");
}
__device__ __forceinline__ void ld_sc_x4_issue(const f32x4* p, f32x4& v) {
  asm volatile("global_load_dwordx4 %0, %1, off sc0 sc1" : "=v"(v) : "v"(p) : "memory");
}
__device__ __forceinline__ void ld_sc_x1_issue(const float* p, float& v) {
  asm volatile("global_load_dword %0, %1, off sc0 sc1" : "=v"(v) : "v"(p) : "memory");
}
__device__ __forceinline__ uint ld_sc_u32(const uint* p) {
  uint v;
  asm volatile("global_load_dword %0, %1, off sc0 sc1\n\ts_waitcnt vmcnt(0)"
               : "=v"(v) : "v"(p) : "memory");
  return v;
}
__device__ __forceinline__ void st_sc_u32(uint* p, uint v) {
  asm volatile("global_store_dword %0, %1, off sc0 sc1" :: "v"(p), "v"(v) : "memory");
}

// plain cached load (L2-served), issue-only
__device__ __forceinline__ void ld_g(const u32x4* p, u32x4& v) {
  asm volatile("global_load_dwordx4 %0, %1, off" : "=v"(v) : "v"(p) : "memory");
}

// ---------- FUSED grid-barrier + activation stage ----------
// Producer contract (before call): activation chunk stored via st_sc and
// DRAINED (counted vmcnt), so data is IC-visible before the flag store.
// Thread tid <-> producer WG tid: poll flags[tid], then immediately load
// WG tid's contiguous chunk and write it to LDS. One s_barrier saved, wave
// resumes on ITS 64 producers (not all 256), poll+load pipeline per thread.

__device__ __forceinline__ void sync_stage_4096(uint* flags, uint tag, int wg,
                                                int tid, const float* src,
                                                float* xs) {
  wgbar();                              // all waves of this WG drained
  if (tid == 0) st_sc_u32(flags + wg * 16, tag);
  const uint* fp = flags + tid * 16;
  if (ld_sc_u32(fp) < tag) {
    do { __builtin_amdgcn_s_sleep(1); } while (ld_sc_u32(fp) < tag);
  }
  const f32x4* s = (const f32x4*)src + tid * 4;   // WG tid's 64B chunk
  f32x4 a, b, c, d;
  ld_sc_x4_issue(s + 0, a); ld_sc_x4_issue(s + 1, b);
  ld_sc_x4_issue(s + 2, c); ld_sc_x4_issue(s + 3, d);
  wait_vm0();
  f32x4* l = (f32x4*)xs + tid * 4;
  l[0] = a; l[1] = b; l[2] = c; l[3] = d;         // ~8-way bank conflict, accepted
  wait_lgkm0();
  wgbar();
}

__device__ __forceinline__ void sync_stage_2048(uint* flags, uint tag, int wg,
                                                int tid, const float* src,
                                                float* xs) {
  wgbar();
  if (tid == 0) st_sc_u32(flags + wg * 16, tag);
  const uint* fp = flags + tid * 16;
  if (ld_sc_u32(fp) < tag) {
    do { __builtin_amdgcn_s_sleep(1); } while (ld_sc_u32(fp) < tag);
  }
  const f32x4* s = (const f32x4*)src + tid * 2;   // WG tid's 32B chunk
  f32x4 a, b;
  ld_sc_x4_issue(s + 0, a); ld_sc_x4_issue(s + 1, b);
  wait_vm0();
  f32x4* l = (f32x4*)xs + tid * 2;
  l[0] = a; l[1] = b;                             // ~4-way bank conflict, accepted
  wait_lgkm0();
  wgbar();
}

// ---------- fp32 -> permuted bf16 u32x4 chunks ----------
// Chunk c = j*64+lane of row r covers x[j*512+lane*4 .. +4) (lo) and
// x[j*512+256+lane*4 .. +4) (hi) -> dot reads x4[j*128+lane], x4[j*128+64+lane]
// (both stride-16B across lanes: LDS-conflict-free).

__device__ __forceinline__ uint bfr(float f) {
  uint u = __float_as_uint(f);
  return (u + 0x7fffu + ((u >> 16) & 1u)) >> 16;
}

__global__ void cvt_perm(const float* __restrict__ in, u32x4* __restrict__ out,
                         int rows, int K) {
  int idx = blockIdx.x * 256 + threadIdx.x;
  int cpr = K >> 3;                      // u32x4 chunks per row
  if (idx >= rows * cpr) return;
  int row = idx / cpr, c = idx - row * cpr;
  int j = c >> 6, lane = c & 63;
  const f32x4* p = (const f32x4*)(in + (size_t)row * K + j * 512 + lane * 4);
  f32x4 lo = p[0];
  f32x4 hi = p[64];                      // +256 elements
  u32x4 o;
  o.x = bfr(lo.x) | (bfr(lo.y) << 16);
  o.y = bfr(lo.z) | (bfr(lo.w) << 16);
  o.z = bfr(hi.x) | (bfr(hi.y) << 16);
  o.w = bfr(hi.z) | (bfr(hi.w) << 16);
  out[idx] = o;
}

// ---------- dot macros ----------
// QF consumes free vars xa, xb (f32x4) from enclosing scope.

#define QF(Q, s) do{                                                 \
  s = fmaf(__uint_as_float((Q).x << 16),         xa.x, s);           \
  s = fmaf(__uint_as_float((Q).x & 0xffff0000u), xa.y, s);           \
  s = fmaf(__uint_as_float((Q).y << 16),         xa.z, s);           \
  s = fmaf(__uint_as_float((Q).y & 0xffff0000u), xa.w, s);           \
  s = fmaf(__uint_as_float((Q).z << 16),         xb.x, s);           \
  s = fmaf(__uint_as_float((Q).z & 0xffff0000u), xb.y, s);           \
  s = fmaf(__uint_as_float((Q).w << 16),         xb.z, s);           \
  s = fmaf(__uint_as_float((Q).w & 0xffff0000u), xb.w, s);           \
}while(0)

// single-row chunk (L0 row-major pipeline)
#define DC(Q, j, s) do{                                              \
  f32x4 xa = x4[(j)*128 + lane];                                     \
  f32x4 xb = x4[(j)*128 + 64 + lane];                                \
  QF(Q, s);                                                          \
}while(0)

// L1: 4 rows/wave from LDS, x read ONCE per chunk (shared across rows)
#define DL4(j) do{                                                   \
  f32x4 xa = x4[(j)*128 + lane];                                     \
  f32x4 xb = x4[(j)*128 + 64 + lane];                                \
  u32x4 Q0 = w1p[0*512 + (j)*64 + lane];                             \
  u32x4 Q1 = w1p[1*512 + (j)*64 + lane];                             \
  u32x4 Q2 = w1p[2*512 + (j)*64 + lane];                             \
  u32x4 Q3 = w1p[3*512 + (j)*64 + lane];                             \
  QF(Q0, s0); QF(Q1, s1); QF(Q2, s2); QF(Q3, s3);                    \
}while(0)

// L2: 4 resident rows, x read once per chunk
#define DR4(j, Qa, Qb, Qc, Qd) do{                                   \
  f32x4 xa = x4[(j)*128 + lane];                                     \
  f32x4 xb = x4[(j)*128 + 64 + lane];                                \
  QF(Qa, s0); QF(Qb, s1); QF(Qc, s2); QF(Qd, s3);                    \
}while(0)

// LF: 2 resident rows, x read once per chunk
#define DR2(j, Qa, Qb) do{                                           \
  f32x4 xa = x4[(j)*128 + lane];                                     \
  f32x4 xb = x4[(j)*128 + 64 + lane];                                \
  QF(Qa, s0); QF(Qb, s1);                                            \
}while(0)

#define SREG(x) __int_as_float(__builtin_amdgcn_readfirstlane(__float_as_int(x)))

// ======================================================================
// RESIDENT kernel, TPB=256 (the only TPB whose VGPR budget is 256 — r10):
//   LDS  : W1 (128 KB)
//   VGPRs: W2 (32 u32x4 = 128) + W3 (16 u32x4 = 64) = 192 named regs
//   L2   : W0 streamed per step (2 MB/XCD, never invalidated -> L2-hit)
// Sync: fused barrier+stage (this round) — one IC hop each, no aggregator.
// ======================================================================

__global__ void __launch_bounds__(TPB_R, 1) ode_res(
    const float* __restrict__ ts, const float* __restrict__ y0,
    const u32x4* __restrict__ W0p, const float* __restrict__ b0,
    const u32x4* __restrict__ W1p, const float* __restrict__ b1,
    const u32x4* __restrict__ W2p, const float* __restrict__ b2,
    const u32x4* __restrict__ W3p, const float* __restrict__ b3,
    float* __restrict__ out, float* hA, float* hB,
    uint* flags)
{
  __shared__ u32x4 W1lds[16 * 512];   // 128 KB: [row within WG][chunk]
  __shared__ float xs[WIDTH];         // 16 KB
  const int wg = blockIdx.x, tid = threadIdx.x;
  const int wave = tid >> 6, lane = tid & 63;
  const float dt = ts[1] - ts[0];
  const int rw = wg * 16 + wave * 4;   // wide layers: 4 rows/wave
  const int rf = wg * 8 + wave * 2;    // final layer: 2 rows/wave
  const f32x4* x4 = (const f32x4*)xs;
  const u32x4* w1p = &W1lds[(wave * 4) * 512];

  // ---- prologue: W1 -> LDS (linear copy of this WG's 16 rows) ----
#pragma unroll
  for (int k = 0; k < 32; ++k)
    W1lds[k * 256 + tid] = W1p[(size_t)wg * 8192 + k * 256 + tid];

  // ---- W2 resident: 32 named u32x4 (128 VGPRs) ----
#define L2W(r,j) W2p[(size_t)(rw+(r))*512 + (j)*64 + lane]
  u32x4 C00=L2W(0,0),C01=L2W(0,1),C02=L2W(0,2),C03=L2W(0,3),C04=L2W(0,4),C05=L2W(0,5),C06=L2W(0,6),C07=L2W(0,7);
  u32x4 C10=L2W(1,0),C11=L2W(1,1),C12=L2W(1,2),C13=L2W(1,3),C14=L2W(1,4),C15=L2W(1,5),C16=L2W(1,6),C17=L2W(1,7);
  u32x4 C20=L2W(2,0),C21=L2W(2,1),C22=L2W(2,2),C23=L2W(2,3),C24=L2W(2,4),C25=L2W(2,5),C26=L2W(2,6),C27=L2W(2,7);
  u32x4 C30=L2W(3,0),C31=L2W(3,1),C32=L2W(3,2),C33=L2W(3,3),C34=L2W(3,4),C35=L2W(3,5),C36=L2W(3,6),C37=L2W(3,7);
  // ---- W3 resident: 16 named u32x4 (64 VGPRs) ----
#define L3W(r,j) W3p[(size_t)(rf+(r))*512 + (j)*64 + lane]
  u32x4 D00=L3W(0,0),D01=L3W(0,1),D02=L3W(0,2),D03=L3W(0,3),D04=L3W(0,4),D05=L3W(0,5),D06=L3W(0,6),D07=L3W(0,7);
  u32x4 D10=L3W(1,0),D11=L3W(1,1),D12=L3W(1,2),D13=L3W(1,3),D14=L3W(1,4),D15=L3W(1,5),D16=L3W(1,6),D17=L3W(1,7);

  // ---- biases in SGPRs (wave-uniform) ----
  const float b00=SREG(b0[rw]), b01=SREG(b0[rw+1]), b02=SREG(b0[rw+2]), b03=SREG(b0[rw+3]);
  const float b10=SREG(b1[rw]), b11=SREG(b1[rw+1]), b12=SREG(b1[rw+2]), b13=SREG(b1[rw+3]);
  const float b20=SREG(b2[rw]), b21=SREG(b2[rw+1]), b22=SREG(b2[rw+2]), b23=SREG(b2[rw+3]);
  const float b30=SREG(b3[rf]), b31=SREG(b3[rf+1]);

  wait_vm0(); wait_lgkm0();
  wgbar();                              // W1lds + residents ready

  // W0 stream: 4 rows/wave, 4 chunks/row, pipelined with counted vmcnt.
  const u32x4* w0base = W0p + (size_t)rw * 256 + lane;
#define ISSW0(r, Qa, Qb, Qc, Qd) do{ const u32x4* p_ = w0base + (size_t)(r)*256; \
  ld_g(p_, Qa); ld_g(p_+64, Qb); ld_g(p_+128, Qc); ld_g(p_+192, Qd); }while(0)

  u32x4 E0a,E0b,E0c,E0d, E1a,E1b,E1c,E1d, E2a,E2b,E2c,E2d, E3a,E3b,E3c,E3d;
  ISSW0(0, E0a,E0b,E0c,E0d);            // prologue prefetch (lands under stage)

  uint tag = 0;
  const float* yin = y0;
  for (int step = 0; step < NSTEP; ++step) {
    float s0, s1, s2, s3;
    // ---- L0: 2048 -> 4096, softplus (W0 L2-streamed, pipelined) ----
    // sync announces prev LF done (tag), then stages y; tag 0 passes trivially.
    sync_stage_2048(flags, tag, wg, tid, yin, xs); ++tag;
    ISSW0(1, E1a,E1b,E1c,E1d);
    s0 = 0.f; DC(E0a,0,s0); DC(E0b,1,s0); DC(E0c,2,s0); DC(E0d,3,s0);
    ISSW0(2, E2a,E2b,E2c,E2d);
    wait_vmN<4>();                      // E1 landed, E2 in flight
    s1 = 0.f; DC(E1a,0,s1); DC(E1b,1,s1); DC(E1c,2,s1); DC(E1d,3,s1);
    ISSW0(3, E3a,E3b,E3c,E3d);
    wait_vmN<4>();                      // E2 landed, E3 in flight
    s2 = 0.f; DC(E2a,0,s2); DC(E2b,1,s2); DC(E2c,2,s2); DC(E2d,3,s2);
    wait_vm0();                         // E3 landed
    s3 = 0.f; DC(E3a,0,s3); DC(E3b,1,s3); DC(E3c,2,s3); DC(E3d,3,s3);
    s0 = wred(s0); s1 = wred(s1); s2 = wred(s2); s3 = wred(s3);
    if (lane == 0) {
      f32x4 v; v.x = sp_f(s0+b00); v.y = sp_f(s1+b01); v.z = sp_f(s2+b02); v.w = sp_f(s3+b03);
      st_sc_x4(hA + rw, v);
    }
    wait_vm0();                         // drain hA chunk before flag

    // ---- L1: 4096 -> 4096, softplus (W1 in LDS, x shared per chunk) ----
    sync_stage_4096(flags, tag, wg, tid, hA, xs); ++tag;
    s0=0.f; s1=0.f; s2=0.f; s3=0.f;
    DL4(0); DL4(1); DL4(2); DL4(3); DL4(4); DL4(5); DL4(6); DL4(7);
    s0 = wred(s0); s1 = wred(s1); s2 = wred(s2); s3 = wred(s3);
    if (lane == 0) {
      f32x4 v; v.x = sp_f(s0+b10); v.y = sp_f(s1+b11); v.z = sp_f(s2+b12); v.w = sp_f(s3+b13);
      st_sc_x4(hB + rw, v);
    }
    wait_vm0();

    // ---- L2: 4096 -> 4096, softplus (W2 in regs, x shared per chunk) ----
    sync_stage_4096(flags, tag, wg, tid, hB, xs); ++tag;
    s0=0.f; s1=0.f; s2=0.f; s3=0.f;
    DR4(0, C00, C10, C20, C30); DR4(1, C01, C11, C21, C31);
    DR4(2, C02, C12, C22, C32); DR4(3, C03, C13, C23, C33);
    DR4(4, C04, C14, C24, C34); DR4(5, C05, C15, C25, C35);
    DR4(6, C06, C16, C26, C36); DR4(7, C07, C17, C27, C37);
    s0 = wred(s0); s1 = wred(s1); s2 = wred(s2); s3 = wred(s3);
    if (lane == 0) {
      f32x4 v; v.x = sp_f(s0+b20); v.y = sp_f(s1+b21); v.z = sp_f(s2+b22); v.w = sp_f(s3+b23);
      st_sc_x4(hA + rw, v);
    }
    wait_vm0();

    // ---- LF: 4096 -> 2048, y += dt*(W3 h + b3) (W3 in regs) ----
    sync_stage_4096(flags, tag, wg, tid, hA, xs); ++tag;
    f32x2 yo;
    ld_sc_x2_issue(yin + rf, yo);       // in flight during the dots
    s0=0.f; s1=0.f;
    DR2(0, D00, D10); DR2(1, D01, D11); DR2(2, D02, D12); DR2(3, D03, D13);
    DR2(4, D04, D14); DR2(5, D05, D15); DR2(6, D06, D16); DR2(7, D07, D17);
    s0 = wred(s0); s1 = wred(s1);
    wait_vm0();                         // yo ready
    float* yout = out + (size_t)step * NDATA;
    if (lane == 0) {
      f32x2 v; v.x = yo.x + dt * (s0 + b30); v.y = yo.y + dt * (s1 + b31);
      st_sc_x2(yout + rf, v);
    }
    ISSW0(0, E0a,E0b,E0c,E0d);          // next step's W0 row 0 (L2-hit)
    wait_vmN<4>();                      // drain y store; keep E0 in flight
    yin = yout;                         // y state lives in d_out rows
  }
}

// ======================================================================
// FALLBACK (ws too small): fp32 streaming kernel, TPB=1024 (r12 design).
// ======================================================================

__device__ __forceinline__ void gbar1k(uint* flags, uint tag, int wg, int tid) {
  wgbar();
  if (tid == 0) st_sc_u32(flags + wg * 16, tag);
  if (tid < NWG) {
    const uint* fp = flags + tid * 16;
    if (ld_sc_u32(fp) < tag) {
      do { __builtin_amdgcn_s_sleep(1); } while (ld_sc_u32(fp) < tag);
    }
  }
  wgbar();
}

__device__ __forceinline__ void stage4096_1k(const float* src, float* xs, int tid) {
  f32x4 a;
  ld_sc_x4_issue((const f32x4*)src + tid, a);
  wait_vm0();
  ((f32x4*)xs)[tid] = a;
  wait_lgkm0();
  wgbar();
}
__device__ __forceinline__ void stage2048_1k(const float* src, float* xs, int tid) {
  f32x4 a;
  bool act = tid < 512;
  if (act) ld_sc_x4_issue((const f32x4*)src + tid, a);
  wait_vm0();
  if (act) ((f32x4*)xs)[tid] = a;
  wait_lgkm0();
  wgbar();
}

__device__ __forceinline__ void issue_row_f32(const float* W, size_t elemidx, int lane, f32x4* wr, int ni) {
  const f32x4* p = (const f32x4*)(W + elemidx) + lane;
  for (int i = 0; i < ni; ++i)
    asm volatile("global_load_dwordx4 %0, %1, off" : "=v"(wr[i]) : "v"(p + i * 64) : "memory");
}

template<int NI>
__device__ __forceinline__ float dot_row_f32(const f32x4* wr, const float* xs, int xoff, int lane) {
  const f32x4* x4 = (const f32x4*)xs + xoff;
  float a = 0.f;
#pragma unroll
  for (int i = 0; i < NI; ++i) {
    f32x4 xv = x4[i * 64 + lane];
    a = fmaf(wr[i].x, xv.x, a); a = fmaf(wr[i].y, xv.y, a);
    a = fmaf(wr[i].z, xv.z, a); a = fmaf(wr[i].w, xv.w, a);
  }
  return a;
}

__global__ void __launch_bounds__(TPB_S, 1) ode_stream(
    const float* __restrict__ ts, const float* __restrict__ y0,
    const float* __restrict__ W0, const float* __restrict__ b0,
    const float* __restrict__ W1, const float* __restrict__ b1,
    const float* __restrict__ W2, const float* __restrict__ b2,
    const float* __restrict__ W3, const float* __restrict__ b3,
    float* __restrict__ out, float* hA, float* hB,
    uint* flags)
{
  __shared__ float xs[WIDTH];
  __shared__ float ps[16];
  const int wg = blockIdx.x, tid = threadIdx.x;
  const int wave = tid >> 6, lane = tid & 63;
  const float dt = ts[1] - ts[0];
  const int rw = wg * 16 + wave;
  const int rF = wg * 8 + (wave >> 1);
  const int hf = wave & 1;

  f32x4 w0r[8], w1r[16], w2r[16], w3r[8];
  issue_row_f32(W0, (size_t)rw * NDATA, lane, w0r, 8);

  uint tag = 0;
  const float* yin = y0;
  for (int step = 0; step < NSTEP; ++step) {
    stage2048_1k(yin, xs, tid);
    float a = wred(dot_row_f32<8>(w0r, xs, 0, lane));
    if (lane == 0) st_sc_x1(hA + rw, sp_f(a + b0[rw]));
    issue_row_f32(W1, (size_t)rw * WIDTH, lane, w1r, 16);
    wait_vmN<16>();
    gbar1k(flags, ++tag, wg, tid);

    stage4096_1k(hA, xs, tid);
    a = wred(dot_row_f32<16>(w1r, xs, 0, lane));
    if (lane == 0) st_sc_x1(hB + rw, sp_f(a + b1[rw]));
    issue_row_f32(W2, (size_t)rw * WIDTH, lane, w2r, 16);
    wait_vmN<16>();
    gbar1k(flags, ++tag, wg, tid);

    stage4096_1k(hB, xs, tid);
    a = wred(dot_row_f32<16>(w2r, xs, 0, lane));
    if (lane == 0) st_sc_x1(hA + rw, sp_f(a + b2[rw]));
    issue_row_f32(W3, (size_t)rF * WIDTH + (size_t)hf * 2048, lane, w3r, 8);
    wait_vmN<8>();
    gbar1k(flags, ++tag, wg, tid);

    stage4096_1k(hA, xs, tid);
    float yo;
    ld_sc_x1_issue(yin + rF, yo);
    a = wred(dot_row_f32<8>(w3r, xs, hf * 512, lane));
    if (lane == 0) ps[wave] = a;
    wait_lgkm0();
    wgbar();
    wait_vm0();
    float* yout = out + (size_t)step * NDATA;
    if (hf == 0 && lane == 0) {
      float tot = ps[wave] + ps[wave + 1];
      st_sc_x1(yout + rF, yo + dt * (tot + b3[rF]));
    }
    issue_row_f32(W0, (size_t)rw * NDATA, lane, w0r, 8);
    wait_vmN<8>();
    gbar1k(flags, ++tag, wg, tid);
    yin = yout;
  }
}

// ---------- launch ----------

#define WS_HA   0
#define WS_HB   16384
#define WS_CNT  32768
#define WS_WB   65536
static const size_t N_W0 = (size_t)WIDTH * NDATA;   // 8.39M elems
static const size_t N_W1 = (size_t)WIDTH * WIDTH;   // 16.78M
static const size_t N_W3 = (size_t)NDATA * WIDTH;   // 8.39M

extern "C" void kernel_launch(void* const* d_in, const int* in_sizes, int n_in,
                              void* d_out, int out_size, void* d_ws, size_t ws_size,
                              hipStream_t stream) {
  const float* ts = (const float*)d_in[0];
  const float* y0 = (const float*)d_in[1];
  const float* W0 = (const float*)d_in[2];
  const float* b0 = (const float*)d_in[3];
  const float* W1 = (const float*)d_in[4];
  const float* b1 = (const float*)d_in[5];
  const float* W2 = (const float*)d_in[6];
  const float* b2 = (const float*)d_in[7];
  const float* W3 = (const float*)d_in[8];
  const float* b3 = (const float*)d_in[9];
  float* out = (float*)d_out;

  char* ws = (char*)d_ws;
  float* hA    = (float*)(ws + WS_HA);
  float* hB    = (float*)(ws + WS_HB);
  uint*  flags = (uint*)(ws + WS_CNT);              // 256 x 64B lines

  hipMemsetAsync(ws + WS_CNT, 0, 16384, stream);    // zero flags each launch

  const size_t need = WS_WB + (N_W0 + 2 * N_W1 + N_W3) * 2;  // ~100.7 MB
  if (ws_size >= need) {
    u32x4* W0p = (u32x4*)(ws + WS_WB);               // N_W0/8 chunks
    u32x4* W1p = W0p + N_W0 / 8;
    u32x4* W2p = W1p + N_W1 / 8;
    u32x4* W3p = W2p + N_W1 / 8;
    hipLaunchKernelGGL(cvt_perm, dim3((unsigned)(N_W0 / 8 / 256)), dim3(256), 0, stream, W0, W0p, WIDTH, NDATA);
    hipLaunchKernelGGL(cvt_perm, dim3((unsigned)(N_W1 / 8 / 256)), dim3(256), 0, stream, W1, W1p, WIDTH, WIDTH);
    hipLaunchKernelGGL(cvt_perm, dim3((unsigned)(N_W1 / 8 / 256)), dim3(256), 0, stream, W2, W2p, WIDTH, WIDTH);
    hipLaunchKernelGGL(cvt_perm, dim3((unsigned)(N_W3 / 8 / 256)), dim3(256), 0, stream, W3, W3p, NDATA, WIDTH);
    hipLaunchKernelGGL(ode_res, dim3(NWG), dim3(TPB_R), 0, stream,
                       ts, y0, W0p, b0, W1p, b1, W2p, b2, W3p, b3,
                       out, hA, hB, flags);
  } else {
    hipLaunchKernelGGL(ode_stream, dim3(NWG), dim3(TPB_S), 0, stream,
                       ts, y0, W0, b0, W1, b1, W2, b2, W3, b3,
                       out, hA, hB, flags);
  }
}

// Round 14
// 19869.081 us; speedup vs baseline: 1.1107x; 1.1107x over previous
//
#include <hip/hip_runtime.h>

#define NWG   256
#define TPB_R 256     // resident kernel: 4 waves, 1/SIMD -> 256-VGPR budget (proven r10)
#define TPB_S 1024    // fallback streaming kernel
#define NSTEP 1000
#define NDATA 2048
#define WIDTH 4096

typedef __attribute__((ext_vector_type(4))) float f32x4;
typedef __attribute__((ext_vector_type(2))) float f32x2;
typedef __attribute__((ext_vector_type(2))) unsigned int u32x2;
typedef __attribute__((ext_vector_type(4))) unsigned int u32x4;
typedef unsigned int uint;

#define SCHED_FENCE() __builtin_amdgcn_sched_barrier(0)

// ---------- scalar helpers ----------

__device__ __forceinline__ float sp_f(float v) {
  // jax.nn.softplus == max(v,0) + log1p(exp(-|v|))
  return fmaxf(v, 0.0f) + log1pf(expf(-fabsf(v)));
}

__device__ __forceinline__ float wred(float v) {
#pragma unroll
  for (int m = 32; m > 0; m >>= 1) v += __shfl_xor(v, m, 64);
  return v;
}

// pack 2 f32 -> 1 u32 of 2 bf16 (lo in low half) — HW cvt_pk (no builtin, m240)
__device__ __forceinline__ uint pk_bf16(float lo, float hi) {
  uint r;
  asm("v_cvt_pk_bf16_f32 %0, %1, %2" : "=v"(r) : "v"(lo), "v"(hi));
  return r;
}

// ---------- waits / barriers ----------

__device__ __forceinline__ void wait_vm0()   { asm volatile("s_waitcnt vmcnt(0)" ::: "memory"); SCHED_FENCE(); }
template<int N>
__device__ __forceinline__ void wait_vmN()   { asm volatile("s_waitcnt vmcnt(%0)" :: "n"(N) : "memory"); SCHED_FENCE(); }
__device__ __forceinline__ void wait_lgkm0() { asm volatile("s_waitcnt lgkmcnt(0)" ::: "memory"); SCHED_FENCE(); }
__device__ __forceinline__ void wgbar()      { __builtin_amdgcn_s_barrier(); SCHED_FENCE(); }

// ---------- L2-bypass (IC-coherent) I/O: sc0 sc1 ----------

__device__ __forceinline__ void st_sc_x1(float* p, float v) {
  asm volatile("global_store_dword %0, %1, off sc0 sc1" :: "v"(p), "v"(v) : "memory");
}
__device__ __forceinline__ void st_sc_x2(float* p, f32x2 v) {
  asm volatile("global_store_dwordx2 %0, %1, off sc0 sc1" :: "v"(p), "v"(v) : "memory");
}
__device__ __forceinline__ void st_sc_u2(uint* p, u32x2 v) {
  asm volatile("global_store_dwordx2 %0, %1, off sc0 sc1" :: "v"(p), "v"(v) : "memory");
}
__device__ __forceinline__ void ld_sc_x2_issue(const float* p, f32x2& v) {
  asm volatile("global_load_dwordx2 %0, %1, off sc0 sc1" : "=v"(v) : "v"(p) : "memory");
}
__device__ __forceinline__ void ld_sc_x4_issue(const f32x4* p, f32x4& v) {
  asm volatile("global_load_dwordx4 %0, %1, off sc0 sc1" : "=v"(v) : "v"(p) : "memory");
}
__device__ __forceinline__ void ld_sc_u4_issue(const u32x4* p, u32x4& v) {
  asm volatile("global_load_dwordx4 %0, %1, off sc0 sc1" : "=v"(v) : "v"(p) : "memory");
}
__device__ __forceinline__ void ld_sc_x1_issue(const float* p, float& v) {
  asm volatile("global_load_dword %0, %1, off sc0 sc1" : "=v"(v) : "v"(p) : "memory");
}
__device__ __forceinline__ uint ld_sc_u32(const uint* p) {
  uint v;
  asm volatile("global_load_dword %0, %1, off sc0 sc1\n\ts_waitcnt vmcnt(0)"
               : "=v"(v) : "v"(p) : "memory");
  return v;
}
__device__ __forceinline__ void st_sc_u32(uint* p, uint v) {
  asm volatile("global_store_dword %0, %1, off sc0 sc1" :: "v"(p), "v"(v) : "memory");
}

// plain cached load (L2-served), issue-only
__device__ __forceinline__ void ld_g(const u32x4* p, u32x4& v) {
  asm volatile("global_load_dwordx4 %0, %1, off" : "=v"(v) : "v"(p) : "memory");
}

// ---------- FUSED grid-barrier + activation stage (bf16 exchange) ----------
// Producer contract: activation chunk stored (bf16-packed for h; f32 for y)
// and DRAINED before the flag store. Thread tid <-> producer WG tid: poll
// flags[tid], then load that WG's contiguous chunk, write to LDS (bf16).

// h vectors (4096 bf16 = 2048 u32): producer chunk = 32B (8 u32).
__device__ __forceinline__ void sync_stage_h(uint* flags, uint tag, int wg,
                                             int tid, const uint* src,
                                             uint* xs) {
  wgbar();
  if (tid == 0) st_sc_u32(flags + wg * 16, tag);
  const uint* fp = flags + tid * 16;
  if (ld_sc_u32(fp) < tag) {
    do { __builtin_amdgcn_s_sleep(1); } while (ld_sc_u32(fp) < tag);
  }
  const u32x4* s = (const u32x4*)src + tid * 2;
  u32x4 a, b;
  ld_sc_u4_issue(s + 0, a); ld_sc_u4_issue(s + 1, b);
  wait_vm0();
  u32x4* l = (u32x4*)xs + tid * 2;
  l[0] = a; l[1] = b;                   // 16-way write conflict, accepted
  wait_lgkm0();
  wgbar();
}

// y vector (2048 f32, exact in d_out): load f32, convert to bf16 pairs here.
__device__ __forceinline__ void sync_stage_y(uint* flags, uint tag, int wg,
                                             int tid, const float* src,
                                             uint* xs) {
  wgbar();
  if (tid == 0) st_sc_u32(flags + wg * 16, tag);
  const uint* fp = flags + tid * 16;
  if (ld_sc_u32(fp) < tag) {
    do { __builtin_amdgcn_s_sleep(1); } while (ld_sc_u32(fp) < tag);
  }
  const f32x4* s = (const f32x4*)src + tid * 2;
  f32x4 a, b;
  ld_sc_x4_issue(s + 0, a); ld_sc_x4_issue(s + 1, b);
  wait_vm0();
  u32x4 o;
  o.x = pk_bf16(a.x, a.y); o.y = pk_bf16(a.z, a.w);
  o.z = pk_bf16(b.x, b.y); o.w = pk_bf16(b.z, b.w);
  ((u32x4*)xs)[tid] = o;                // 8-way write conflict, accepted
  wait_lgkm0();
  wgbar();
}

// ---------- fp32 -> permuted bf16 u32x4 chunks (weights) ----------
// Chunk c = j*64+lane of row r covers x[j*512+lane*4 .. +4) (lo) and
// x[j*512+256+lane*4 .. +4) (hi); x read as u32x2 bf16-pair words.

__device__ __forceinline__ uint bfr(float f) {
  uint u = __float_as_uint(f);
  return (u + 0x7fffu + ((u >> 16) & 1u)) >> 16;
}

__global__ void cvt_perm(const float* __restrict__ in, u32x4* __restrict__ out,
                         int rows, int K) {
  int idx = blockIdx.x * 256 + threadIdx.x;
  int cpr = K >> 3;                      // u32x4 chunks per row
  if (idx >= rows * cpr) return;
  int row = idx / cpr, c = idx - row * cpr;
  int j = c >> 6, lane = c & 63;
  const f32x4* p = (const f32x4*)(in + (size_t)row * K + j * 512 + lane * 4);
  f32x4 lo = p[0];
  f32x4 hi = p[64];                      // +256 elements
  u32x4 o;
  o.x = bfr(lo.x) | (bfr(lo.y) << 16);
  o.y = bfr(lo.z) | (bfr(lo.w) << 16);
  o.z = bfr(hi.x) | (bfr(hi.y) << 16);
  o.w = bfr(hi.z) | (bfr(hi.w) << 16);
  out[idx] = o;
}

// ---------- dot macros: v_dot2_f32_bf16 (2 MACs / instruction, no unpack) ----

#define VD(W, X, s) asm("v_dot2_f32_bf16 %0, %1, %2, %0" : "+v"(s) : "v"(W), "v"(X))

#define QF(Q, s) do{                                                 \
  VD((Q).x, xa2.x, s); VD((Q).y, xa2.y, s);                          \
  VD((Q).z, xb2.x, s); VD((Q).w, xb2.y, s);                          \
}while(0)

// single-row chunk (L0 row-major pipeline); xw2 = (const u32x2*)xs
#define DC(Q, j, s) do{                                              \
  u32x2 xa2 = xw2[(j)*128 + lane];                                   \
  u32x2 xb2 = xw2[(j)*128 + 64 + lane];                              \
  QF(Q, s);                                                          \
}while(0)

// L1: 4 rows/wave from LDS, x read ONCE per chunk (shared across rows)
#define DL4(j) do{                                                   \
  u32x2 xa2 = xw2[(j)*128 + lane];                                   \
  u32x2 xb2 = xw2[(j)*128 + 64 + lane];                              \
  u32x4 Q0 = w1p[0*512 + (j)*64 + lane];                             \
  u32x4 Q1 = w1p[1*512 + (j)*64 + lane];                             \
  u32x4 Q2 = w1p[2*512 + (j)*64 + lane];                             \
  u32x4 Q3 = w1p[3*512 + (j)*64 + lane];                             \
  QF(Q0, s0); QF(Q1, s1); QF(Q2, s2); QF(Q3, s3);                    \
}while(0)

// L2: 4 resident rows, x read once per chunk
#define DR4(j, Qa, Qb, Qc, Qd) do{                                   \
  u32x2 xa2 = xw2[(j)*128 + lane];                                   \
  u32x2 xb2 = xw2[(j)*128 + 64 + lane];                              \
  QF(Qa, s0); QF(Qb, s1); QF(Qc, s2); QF(Qd, s3);                    \
}while(0)

// LF: 2 resident rows, x read once per chunk
#define DR2(j, Qa, Qb) do{                                           \
  u32x2 xa2 = xw2[(j)*128 + lane];                                   \
  u32x2 xb2 = xw2[(j)*128 + 64 + lane];                              \
  QF(Qa, s0); QF(Qb, s1);                                            \
}while(0)

#define SREG(x) __int_as_float(__builtin_amdgcn_readfirstlane(__float_as_int(x)))

// ======================================================================
// RESIDENT kernel, TPB=256:
//   LDS  : W1 (128 KB) + xs (8 KB bf16 activation vector)
//   VGPRs: W2 (32 u32x4) + W3 (16 u32x4) = 192 named regs
//   L2   : W0 streamed per step (2 MB/XCD, never invalidated -> L2-hit)
// Compute: v_dot2_f32_bf16 (1 inst / 2 MACs); activations exchanged as bf16.
// ======================================================================

__global__ void __launch_bounds__(TPB_R, 1) ode_res(
    const float* __restrict__ ts, const float* __restrict__ y0,
    const u32x4* __restrict__ W0p, const float* __restrict__ b0,
    const u32x4* __restrict__ W1p, const float* __restrict__ b1,
    const u32x4* __restrict__ W2p, const float* __restrict__ b2,
    const u32x4* __restrict__ W3p, const float* __restrict__ b3,
    float* __restrict__ out, uint* hA, uint* hB,
    uint* flags)
{
  __shared__ u32x4 W1lds[16 * 512];   // 128 KB: [row within WG][chunk]
  __shared__ uint xs[2048];           // 8 KB: activation vector, bf16 pairs
  const int wg = blockIdx.x, tid = threadIdx.x;
  const int wave = tid >> 6, lane = tid & 63;
  const float dt = ts[1] - ts[0];
  const int rw = wg * 16 + wave * 4;   // wide layers: 4 rows/wave
  const int rf = wg * 8 + wave * 2;    // final layer: 2 rows/wave
  const u32x2* xw2 = (const u32x2*)xs;
  const u32x4* w1p = &W1lds[(wave * 4) * 512];

  // ---- prologue: W1 -> LDS (linear copy of this WG's 16 rows) ----
#pragma unroll
  for (int k = 0; k < 32; ++k)
    W1lds[k * 256 + tid] = W1p[(size_t)wg * 8192 + k * 256 + tid];

  // ---- W2 resident: 32 named u32x4 (128 VGPRs) ----
#define L2W(r,j) W2p[(size_t)(rw+(r))*512 + (j)*64 + lane]
  u32x4 C00=L2W(0,0),C01=L2W(0,1),C02=L2W(0,2),C03=L2W(0,3),C04=L2W(0,4),C05=L2W(0,5),C06=L2W(0,6),C07=L2W(0,7);
  u32x4 C10=L2W(1,0),C11=L2W(1,1),C12=L2W(1,2),C13=L2W(1,3),C14=L2W(1,4),C15=L2W(1,5),C16=L2W(1,6),C17=L2W(1,7);
  u32x4 C20=L2W(2,0),C21=L2W(2,1),C22=L2W(2,2),C23=L2W(2,3),C24=L2W(2,4),C25=L2W(2,5),C26=L2W(2,6),C27=L2W(2,7);
  u32x4 C30=L2W(3,0),C31=L2W(3,1),C32=L2W(3,2),C33=L2W(3,3),C34=L2W(3,4),C35=L2W(3,5),C36=L2W(3,6),C37=L2W(3,7);
  // ---- W3 resident: 16 named u32x4 (64 VGPRs) ----
#define L3W(r,j) W3p[(size_t)(rf+(r))*512 + (j)*64 + lane]
  u32x4 D00=L3W(0,0),D01=L3W(0,1),D02=L3W(0,2),D03=L3W(0,3),D04=L3W(0,4),D05=L3W(0,5),D06=L3W(0,6),D07=L3W(0,7);
  u32x4 D10=L3W(1,0),D11=L3W(1,1),D12=L3W(1,2),D13=L3W(1,3),D14=L3W(1,4),D15=L3W(1,5),D16=L3W(1,6),D17=L3W(1,7);

  // ---- biases in SGPRs (wave-uniform) ----
  const float b00=SREG(b0[rw]), b01=SREG(b0[rw+1]), b02=SREG(b0[rw+2]), b03=SREG(b0[rw+3]);
  const float b10=SREG(b1[rw]), b11=SREG(b1[rw+1]), b12=SREG(b1[rw+2]), b13=SREG(b1[rw+3]);
  const float b20=SREG(b2[rw]), b21=SREG(b2[rw+1]), b22=SREG(b2[rw+2]), b23=SREG(b2[rw+3]);
  const float b30=SREG(b3[rf]), b31=SREG(b3[rf+1]);

  wait_vm0(); wait_lgkm0();
  wgbar();                              // W1lds + residents ready

  // W0 stream: 4 rows/wave, 4 chunks/row, pipelined with counted vmcnt.
  const u32x4* w0base = W0p + (size_t)rw * 256 + lane;
#define ISSW0(r, Qa, Qb, Qc, Qd) do{ const u32x4* p_ = w0base + (size_t)(r)*256; \
  ld_g(p_, Qa); ld_g(p_+64, Qb); ld_g(p_+128, Qc); ld_g(p_+192, Qd); }while(0)

  u32x4 E0a,E0b,E0c,E0d, E1a,E1b,E1c,E1d, E2a,E2b,E2c,E2d, E3a,E3b,E3c,E3d;
  ISSW0(0, E0a,E0b,E0c,E0d);            // prologue prefetch (lands under stage)

  uint tag = 0;
  const float* yin = y0;
  for (int step = 0; step < NSTEP; ++step) {
    float s0, s1, s2, s3;
    // ---- L0: 2048 -> 4096, softplus (W0 L2-streamed, pipelined) ----
    sync_stage_y(flags, tag, wg, tid, yin, xs); ++tag;   // also lands E0
    ISSW0(1, E1a,E1b,E1c,E1d);
    s0 = 0.f; DC(E0a,0,s0); DC(E0b,1,s0); DC(E0c,2,s0); DC(E0d,3,s0);
    ISSW0(2, E2a,E2b,E2c,E2d);
    wait_vmN<4>();                      // E1 landed, E2 in flight
    s1 = 0.f; DC(E1a,0,s1); DC(E1b,1,s1); DC(E1c,2,s1); DC(E1d,3,s1);
    ISSW0(3, E3a,E3b,E3c,E3d);
    wait_vmN<4>();                      // E2 landed, E3 in flight
    s2 = 0.f; DC(E2a,0,s2); DC(E2b,1,s2); DC(E2c,2,s2); DC(E2d,3,s2);
    wait_vm0();                         // E3 landed
    s3 = 0.f; DC(E3a,0,s3); DC(E3b,1,s3); DC(E3c,2,s3); DC(E3d,3,s3);
    s0 = wred(s0); s1 = wred(s1); s2 = wred(s2); s3 = wred(s3);
    if (lane == 0) {
      u32x2 v; v.x = pk_bf16(sp_f(s0+b00), sp_f(s1+b01));
               v.y = pk_bf16(sp_f(s2+b02), sp_f(s3+b03));
      st_sc_u2(hA + (rw >> 1), v);
    }
    wait_vm0();                         // drain hA chunk before flag

    // ---- L1: 4096 -> 4096, softplus (W1 in LDS, x shared per chunk) ----
    sync_stage_h(flags, tag, wg, tid, hA, xs); ++tag;
    s0=0.f; s1=0.f; s2=0.f; s3=0.f;
    DL4(0); DL4(1); DL4(2); DL4(3); DL4(4); DL4(5); DL4(6); DL4(7);
    s0 = wred(s0); s1 = wred(s1); s2 = wred(s2); s3 = wred(s3);
    if (lane == 0) {
      u32x2 v; v.x = pk_bf16(sp_f(s0+b10), sp_f(s1+b11));
               v.y = pk_bf16(sp_f(s2+b12), sp_f(s3+b13));
      st_sc_u2(hB + (rw >> 1), v);
    }
    wait_vm0();

    // ---- L2: 4096 -> 4096, softplus (W2 in regs, x shared per chunk) ----
    sync_stage_h(flags, tag, wg, tid, hB, xs); ++tag;
    s0=0.f; s1=0.f; s2=0.f; s3=0.f;
    DR4(0, C00, C10, C20, C30); DR4(1, C01, C11, C21, C31);
    DR4(2, C02, C12, C22, C32); DR4(3, C03, C13, C23, C33);
    DR4(4, C04, C14, C24, C34); DR4(5, C05, C15, C25, C35);
    DR4(6, C06, C16, C26, C36); DR4(7, C07, C17, C27, C37);
    s0 = wred(s0); s1 = wred(s1); s2 = wred(s2); s3 = wred(s3);
    if (lane == 0) {
      u32x2 v; v.x = pk_bf16(sp_f(s0+b20), sp_f(s1+b21));
               v.y = pk_bf16(sp_f(s2+b22), sp_f(s3+b23));
      st_sc_u2(hA + (rw >> 1), v);
    }
    wait_vm0();

    // ---- LF: 4096 -> 2048, y += dt*(W3 h + b3) (W3 in regs) ----
    sync_stage_h(flags, tag, wg, tid, hA, xs); ++tag;
    f32x2 yo;
    ld_sc_x2_issue(yin + rf, yo);       // in flight during the dots
    s0=0.f; s1=0.f;
    DR2(0, D00, D10); DR2(1, D01, D11); DR2(2, D02, D12); DR2(3, D03, D13);
    DR2(4, D04, D14); DR2(5, D05, D15); DR2(6, D06, D16); DR2(7, D07, D17);
    s0 = wred(s0); s1 = wred(s1);
    wait_vm0();                         // yo ready
    float* yout = out + (size_t)step * NDATA;
    if (lane == 0) {
      f32x2 v; v.x = yo.x + dt * (s0 + b30); v.y = yo.y + dt * (s1 + b31);
      st_sc_x2(yout + rf, v);
    }
    ISSW0(0, E0a,E0b,E0c,E0d);          // next step's W0 row 0 (L2-hit)
    wait_vmN<4>();                      // drain y store; keep E0 in flight
    yin = yout;                         // y state lives in d_out rows
  }
}

// ======================================================================
// FALLBACK (ws too small): fp32 streaming kernel, TPB=1024 (r12 design).
// ======================================================================

__device__ __forceinline__ void gbar1k(uint* flags, uint tag, int wg, int tid) {
  wgbar();
  if (tid == 0) st_sc_u32(flags + wg * 16, tag);
  if (tid < NWG) {
    const uint* fp = flags + tid * 16;
    if (ld_sc_u32(fp) < tag) {
      do { __builtin_amdgcn_s_sleep(1); } while (ld_sc_u32(fp) < tag);
    }
  }
  wgbar();
}

__device__ __forceinline__ void stage4096_1k(const float* src, float* xs, int tid) {
  f32x4 a;
  ld_sc_x4_issue((const f32x4*)src + tid, a);
  wait_vm0();
  ((f32x4*)xs)[tid] = a;
  wait_lgkm0();
  wgbar();
}
__device__ __forceinline__ void stage2048_1k(const float* src, float* xs, int tid) {
  f32x4 a;
  bool act = tid < 512;
  if (act) ld_sc_x4_issue((const f32x4*)src + tid, a);
  wait_vm0();
  if (act) ((f32x4*)xs)[tid] = a;
  wait_lgkm0();
  wgbar();
}

__device__ __forceinline__ void issue_row_f32(const float* W, size_t elemidx, int lane, f32x4* wr, int ni) {
  const f32x4* p = (const f32x4*)(W + elemidx) + lane;
  for (int i = 0; i < ni; ++i)
    asm volatile("global_load_dwordx4 %0, %1, off" : "=v"(wr[i]) : "v"(p + i * 64) : "memory");
}

template<int NI>
__device__ __forceinline__ float dot_row_f32(const f32x4* wr, const float* xs, int xoff, int lane) {
  const f32x4* x4 = (const f32x4*)xs + xoff;
  float a = 0.f;
#pragma unroll
  for (int i = 0; i < NI; ++i) {
    f32x4 xv = x4[i * 64 + lane];
    a = fmaf(wr[i].x, xv.x, a); a = fmaf(wr[i].y, xv.y, a);
    a = fmaf(wr[i].z, xv.z, a); a = fmaf(wr[i].w, xv.w, a);
  }
  return a;
}

__global__ void __launch_bounds__(TPB_S, 1) ode_stream(
    const float* __restrict__ ts, const float* __restrict__ y0,
    const float* __restrict__ W0, const float* __restrict__ b0,
    const float* __restrict__ W1, const float* __restrict__ b1,
    const float* __restrict__ W2, const float* __restrict__ b2,
    const float* __restrict__ W3, const float* __restrict__ b3,
    float* __restrict__ out, float* hA, float* hB,
    uint* flags)
{
  __shared__ float xs[WIDTH];
  __shared__ float ps[16];
  const int wg = blockIdx.x, tid = threadIdx.x;
  const int wave = tid >> 6, lane = tid & 63;
  const float dt = ts[1] - ts[0];
  const int rw = wg * 16 + wave;
  const int rF = wg * 8 + (wave >> 1);
  const int hf = wave & 1;

  f32x4 w0r[8], w1r[16], w2r[16], w3r[8];
  issue_row_f32(W0, (size_t)rw * NDATA, lane, w0r, 8);

  uint tag = 0;
  const float* yin = y0;
  for (int step = 0; step < NSTEP; ++step) {
    stage2048_1k(yin, xs, tid);
    float a = wred(dot_row_f32<8>(w0r, xs, 0, lane));
    if (lane == 0) st_sc_x1(hA + rw, sp_f(a + b0[rw]));
    issue_row_f32(W1, (size_t)rw * WIDTH, lane, w1r, 16);
    wait_vmN<16>();
    gbar1k(flags, ++tag, wg, tid);

    stage4096_1k(hA, xs, tid);
    a = wred(dot_row_f32<16>(w1r, xs, 0, lane));
    if (lane == 0) st_sc_x1(hB + rw, sp_f(a + b1[rw]));
    issue_row_f32(W2, (size_t)rw * WIDTH, lane, w2r, 16);
    wait_vmN<16>();
    gbar1k(flags, ++tag, wg, tid);

    stage4096_1k(hB, xs, tid);
    a = wred(dot_row_f32<16>(w2r, xs, 0, lane));
    if (lane == 0) st_sc_x1(hA + rw, sp_f(a + b2[rw]));
    issue_row_f32(W3, (size_t)rF * WIDTH + (size_t)hf * 2048, lane, w3r, 8);
    wait_vmN<8>();
    gbar1k(flags, ++tag, wg, tid);

    stage4096_1k(hA, xs, tid);
    float yo;
    ld_sc_x1_issue(yin + rF, yo);
    a = wred(dot_row_f32<8>(w3r, xs, hf * 512, lane));
    if (lane == 0) ps[wave] = a;
    wait_lgkm0();
    wgbar();
    wait_vm0();
    float* yout = out + (size_t)step * NDATA;
    if (hf == 0 && lane == 0) {
      float tot = ps[wave] + ps[wave + 1];
      st_sc_x1(yout + rF, yo + dt * (tot + b3[rF]));
    }
    issue_row_f32(W0, (size_t)rw * NDATA, lane, w0r, 8);
    wait_vmN<8>();
    gbar1k(flags, ++tag, wg, tid);
    yin = yout;
  }
}

// ---------- launch ----------

#define WS_HA   0
#define WS_HB   16384
#define WS_CNT  32768
#define WS_WB   65536
static const size_t N_W0 = (size_t)WIDTH * NDATA;   // 8.39M elems
static const size_t N_W1 = (size_t)WIDTH * WIDTH;   // 16.78M
static const size_t N_W3 = (size_t)NDATA * WIDTH;   // 8.39M

extern "C" void kernel_launch(void* const* d_in, const int* in_sizes, int n_in,
                              void* d_out, int out_size, void* d_ws, size_t ws_size,
                              hipStream_t stream) {
  const float* ts = (const float*)d_in[0];
  const float* y0 = (const float*)d_in[1];
  const float* W0 = (const float*)d_in[2];
  const float* b0 = (const float*)d_in[3];
  const float* W1 = (const float*)d_in[4];
  const float* b1 = (const float*)d_in[5];
  const float* W2 = (const float*)d_in[6];
  const float* b2 = (const float*)d_in[7];
  const float* W3 = (const float*)d_in[8];
  const float* b3 = (const float*)d_in[9];
  float* out = (float*)d_out;

  char* ws = (char*)d_ws;
  uint*  flags = (uint*)(ws + WS_CNT);              // 256 x 64B lines

  hipMemsetAsync(ws + WS_CNT, 0, 16384, stream);    // zero flags each launch

  const size_t need = WS_WB + (N_W0 + 2 * N_W1 + N_W3) * 2;  // ~100.7 MB
  if (ws_size >= need) {
    u32x4* W0p = (u32x4*)(ws + WS_WB);               // N_W0/8 chunks
    u32x4* W1p = W0p + N_W0 / 8;
    u32x4* W2p = W1p + N_W1 / 8;
    u32x4* W3p = W2p + N_W1 / 8;
    uint* hA = (uint*)(ws + WS_HA);                  // bf16-packed h (8 KB)
    uint* hB = (uint*)(ws + WS_HB);
    hipLaunchKernelGGL(cvt_perm, dim3((unsigned)(N_W0 / 8 / 256)), dim3(256), 0, stream, W0, W0p, WIDTH, NDATA);
    hipLaunchKernelGGL(cvt_perm, dim3((unsigned)(N_W1 / 8 / 256)), dim3(256), 0, stream, W1, W1p, WIDTH, WIDTH);
    hipLaunchKernelGGL(cvt_perm, dim3((unsigned)(N_W1 / 8 / 256)), dim3(256), 0, stream, W2, W2p, WIDTH, WIDTH);
    hipLaunchKernelGGL(cvt_perm, dim3((unsigned)(N_W3 / 8 / 256)), dim3(256), 0, stream, W3, W3p, NDATA, WIDTH);
    hipLaunchKernelGGL(ode_res, dim3(NWG), dim3(TPB_R), 0, stream,
                       ts, y0, W0p, b0, W1p, b1, W2p, b2, W3p, b3,
                       out, hA, hB, flags);
  } else {
    float* hAf = (float*)(ws + WS_HA);
    float* hBf = (float*)(ws + WS_HB);
    hipLaunchKernelGGL(ode_stream, dim3(NWG), dim3(TPB_S), 0, stream,
                       ts, y0, W0, b0, W1, b1, W2, b2, W3, b3,
                       out, hAf, hBf, flags);
  }
}